// Round 1
// baseline (90.917 us; speedup 1.0000x reference)
//
#include <hip/hip_runtime.h>
#include <math.h>

// Hexagonal sensor photon binning.
// Inputs (setup_inputs order):
//   0: x        float32 [N]
//   1: y        float32 [N]
//   2: values   float32 [N]
//   3: lookup   int32   [Q*R]   (square: Q == R == sqrt(count))
//   4: hex_size float32 [1]
//   5: q_offset float32 [1]
//   6: r_offset float32 [1]
//   7: q_min    int32   [1]
//   8: r_min    int32   [1]
//   9: n_pixels int32   [1]
// Output: float32 [n_pixels] segment sums.

__global__ void hex_zero_kernel(float* __restrict__ out, int n) {
    int i = blockIdx.x * blockDim.x + threadIdx.x;
    if (i < n) out[i] = 0.0f;
}

__global__ __launch_bounds__(256) void hex_bin_kernel(
    const float* __restrict__ x,
    const float* __restrict__ y,
    const float* __restrict__ vals,
    const int*   __restrict__ lookup,
    const float* __restrict__ hex_size_p,
    const float* __restrict__ q_off_p,
    const float* __restrict__ r_off_p,
    const int*   __restrict__ q_min_p,
    const int*   __restrict__ r_min_p,
    int Q, int R, int n_pixels, int n_photons,
    float* __restrict__ out)
{
    extern __shared__ float hist[];  // n_pixels floats
    for (int i = threadIdx.x; i < n_pixels; i += blockDim.x) hist[i] = 0.0f;
    __syncthreads();

    const float inv_h = 1.0f / hex_size_p[0];
    const float qoff  = q_off_p[0];
    const float roff  = r_off_p[0];
    const int   qmin  = q_min_p[0];
    const int   rmin  = r_min_p[0];

    const float cq = 0.57735026918962576f;  // sqrt(3)/3
    const float c3 = 0.33333333333333333f;  // 1/3
    const float c23 = 0.66666666666666667f; // 2/3

    auto process = [&](float xf, float yf, float vf) {
        float q = (cq * xf - c3 * yf) * inv_h - qoff;
        float r = (c23 * yf) * inv_h - roff;
        float s = -q - r;
        float qr = rintf(q);   // round-half-even, matches jnp.round
        float rr = rintf(r);
        float sr = rintf(s);
        float qd = fabsf(qr - q);
        float rd = fabsf(rr - r);
        float sd = fabsf(sr - s);
        float q2 = (qd > rd && qd > sd) ? (-rr - sr) : qr;
        float r2 = (rd > qd && rd > sd) ? (-qr - sr) : rr;
        int qi = (int)q2 - qmin;   // truncation == exact for integral floats
        int ri = (int)r2 - rmin;
        if (qi >= 0 && qi < Q && ri >= 0 && ri < R) {
            int p = lookup[qi * R + ri];
            if (p >= 0) atomicAdd(&hist[p], vf);   // ds_add_f32
        }
    };

    const int tid    = blockIdx.x * blockDim.x + threadIdx.x;
    const int stride = gridDim.x * blockDim.x;
    const int n4     = n_photons >> 2;

    const float4* __restrict__ x4 = (const float4*)x;
    const float4* __restrict__ y4 = (const float4*)y;
    const float4* __restrict__ v4 = (const float4*)vals;

    for (int i = tid; i < n4; i += stride) {
        float4 xv = x4[i];
        float4 yv = y4[i];
        float4 vv = v4[i];
        process(xv.x, yv.x, vv.x);
        process(xv.y, yv.y, vv.y);
        process(xv.z, yv.z, vv.z);
        process(xv.w, yv.w, vv.w);
    }
    // tail (N % 4 != 0)
    for (int i = (n4 << 2) + tid; i < n_photons; i += stride) {
        process(x[i], y[i], vals[i]);
    }

    __syncthreads();
    for (int i = threadIdx.x; i < n_pixels; i += blockDim.x) {
        float h = hist[i];
        if (h != 0.0f) atomicAdd(&out[i], h);
    }
}

extern "C" void kernel_launch(void* const* d_in, const int* in_sizes, int n_in,
                              void* d_out, int out_size, void* d_ws, size_t ws_size,
                              hipStream_t stream) {
    const float* x      = (const float*)d_in[0];
    const float* y      = (const float*)d_in[1];
    const float* vals   = (const float*)d_in[2];
    const int*   lookup = (const int*)d_in[3];
    const float* hexs   = (const float*)d_in[4];
    const float* qoff   = (const float*)d_in[5];
    const float* roff   = (const float*)d_in[6];
    const int*   qmin   = (const int*)d_in[7];
    const int*   rmin   = (const int*)d_in[8];

    const int n_photons = in_sizes[0];
    const int lut_elems = in_sizes[3];
    const int Q = (int)(0.5 + sqrt((double)lut_elems));  // square table (49x49)
    const int R = Q;
    const int n_pixels = out_size;

    float* out = (float*)d_out;

    // d_out is poisoned once and never re-zeroed between replays: zero it here.
    {
        int threads = 256;
        int blocks = (n_pixels + threads - 1) / threads;
        hex_zero_kernel<<<blocks, threads, 0, stream>>>(out, n_pixels);
    }

    const int threads = 256;
    const int blocks = 1024;
    const size_t lds_bytes = (size_t)n_pixels * sizeof(float);
    hex_bin_kernel<<<blocks, threads, lds_bytes, stream>>>(
        x, y, vals, lookup, hexs, qoff, roff, qmin, rmin,
        Q, R, n_pixels, n_photons, out);
}